// Round 6
// baseline (115.296 us; speedup 1.0000x reference)
//
#include <hip/hip_runtime.h>

// TreeCRF inside pass, L=32 channels, perfect binary tree (heap layout).
// parent[i] = em[i] + LSE_j(T[i,j]+left[j]) + LSE_j(T[i,j]+right[j])
// LSE_j(T[i,j]+c[j]) = m + log(sum_j E[i,j]*exp(c[j]-m)), E=exp(T), m=max_j c[j].
//
// R6: single-phase levels. In the (parent,channel) mapping each 32-lane group
// holds one full parent row, so the row max (5-step shfl butterfly) and
// exp(val-m) are computed inline and written straight to the next level's C
// buffer: ONE barrier per level, no score buffer at all. C ping-pongs between
// CA [2^L][32] and CB [2^(L-1)][32] (stride-32; all patterns are broadcast or
// <=2-way bank aliasing = free). Bottom kernel sized for 2 blocks/CU so one
// block's barrier stall overlaps the other's compute.

template <int NT, int LEVELS>
__device__ __forceinline__ void run_tree(
    const int t, int Wp, int boff, const int b,
    const float* __restrict__ gchild,   // [2^LEVELS][32] leaf-level rows
    const float* __restrict__ em,
    const float* __restrict__ erow,     // exp(trans[t&31, :]) in registers
    float* __restrict__ CA, float* __restrict__ MA,
    float* __restrict__ CB, float* __restrict__ MB,
    float* __restrict__ gout)           // [32]
{
    const int NC0 = 1 << LEVELS;
    // stage 0: global child rows -> exp rows in CA (8 lanes per row)
    for (int u = t; u < NC0 * 8; u += NT) {
        int ql = u >> 3, k = u & 7;
        float4 x = ((const float4*)(gchild + (size_t)ql * 32))[k];
        float4 r = x;
#define MSTEP(mask) { float4 o; o.x=__shfl_xor(r.x,mask); o.y=__shfl_xor(r.y,mask); \
                      o.z=__shfl_xor(r.z,mask); o.w=__shfl_xor(r.w,mask); \
                      r.x=fmaxf(r.x,o.x); r.y=fmaxf(r.y,o.y); \
                      r.z=fmaxf(r.z,o.z); r.w=fmaxf(r.w,o.w); }
        MSTEP(1) MSTEP(2) MSTEP(4)
#undef MSTEP
        float m = fmaxf(fmaxf(r.x, r.y), fmaxf(r.z, r.w));
        float4 e;
        e.x = __expf(x.x - m); e.y = __expf(x.y - m);
        e.z = __expf(x.z - m); e.w = __expf(x.w - m);
        ((float4*)(CA + ql * 32))[k] = e;
        if (k == 0) MA[ql] = m;
    }
    __syncthreads();

    float* Cs = CA; float* Ms = MA;
    float* Cd = CB; float* Md = MB;
    int nc = NC0;
    for (int l = 0; l < LEVELS; ++l) {
        int np = nc >> 1;
        for (int u = t; u < np * 32; u += NT) {
            int pl = u >> 5, i = u & 31;
            const float4* cl = (const float4*)(Cs + (size_t)(2 * pl) * 32);
            float sl = 0.0f, sr = 0.0f;
#pragma unroll
            for (int k = 0; k < 8; ++k) {
                float4 a = cl[k], d = cl[k + 8];      // rows 2pl, 2pl+1 adjacent
                sl = fmaf(erow[4 * k + 0], a.x, sl);
                sl = fmaf(erow[4 * k + 1], a.y, sl);
                sl = fmaf(erow[4 * k + 2], a.z, sl);
                sl = fmaf(erow[4 * k + 3], a.w, sl);
                sr = fmaf(erow[4 * k + 0], d.x, sr);
                sr = fmaf(erow[4 * k + 1], d.y, sr);
                sr = fmaf(erow[4 * k + 2], d.z, sr);
                sr = fmaf(erow[4 * k + 3], d.w, sr);
            }
            float val = em[(size_t)(Wp - 1 + boff * b + pl) * 32 + i]
                      + Ms[2 * pl] + __logf(sl)
                      + Ms[2 * pl + 1] + __logf(sr);
            if (l == LEVELS - 1) {
                gout[i] = val;
            } else {
                float m = val;                        // 32-lane butterfly max
                m = fmaxf(m, __shfl_xor(m, 16));
                m = fmaxf(m, __shfl_xor(m, 8));
                m = fmaxf(m, __shfl_xor(m, 4));
                m = fmaxf(m, __shfl_xor(m, 2));
                m = fmaxf(m, __shfl_xor(m, 1));
                Cd[pl * 32 + i] = __expf(val - m);
                if (i == 0) Md[pl] = m;
            }
        }
        __syncthreads();
        float* tc = Cs; Cs = Cd; Cd = tc;
        float* tm = Ms; Ms = Md; Md = tm;
        nc = np; Wp >>= 1; boff >>= 1;
    }
}

__device__ __forceinline__ void load_erow(const float* __restrict__ trans,
                                          int lane_i, float* erow)
{
    const float4* tr = (const float4*)(trans + lane_i * 32);
#pragma unroll
    for (int k = 0; k < 8; ++k) {
        float4 v = tr[k];
        erow[4 * k + 0] = __expf(v.x);
        erow[4 * k + 1] = __expf(v.y);
        erow[4 * k + 2] = __expf(v.z);
        erow[4 * k + 3] = __expf(v.w);
    }
}

// Bottom: 512 blocks x 512 thr; 256 contiguous leaves -> one width-512 row.
// LDS 49.5 KB -> 2 blocks/CU resident (barrier overlap between blocks).
__global__ __launch_bounds__(512) void treecrf_bottom(
    const float* __restrict__ em, const float* __restrict__ trans,
    float* __restrict__ out512, int n_leaves)
{
    __shared__ float CA[256 * 32];     // 32 KB
    __shared__ float CB[128 * 32];     // 16 KB
    __shared__ float MA[256];
    __shared__ float MB[128];
    int t = threadIdx.x, b = blockIdx.x;
    float erow[32];
    load_erow(trans, t & 31, erow);
    run_tree<512, 8>(t, n_leaves >> 1, 128, b,
                     em + (size_t)(n_leaves - 1 + 256 * b) * 32, em, erow,
                     CA, MA, CB, MB, out512 + (size_t)b * 32);
}

// Top: 1 block x 1024 thr; 512 width-512 rows -> root, chunk-free (99 KB LDS).
__global__ __launch_bounds__(1024) void treecrf_top(
    const float* __restrict__ g512, const float* __restrict__ em,
    const float* __restrict__ trans, float* __restrict__ out_root)
{
    __shared__ float CA[512 * 32];     // 64 KB
    __shared__ float CB[256 * 32];     // 32 KB
    __shared__ float MA[512];
    __shared__ float MB[256];
    int t = threadIdx.x;
    float erow[32];
    load_erow(trans, t & 31, erow);
    run_tree<1024, 9>(t, 256, 0, 0, g512, em, erow, CA, MA, CB, MB, out_root);
}

extern "C" void kernel_launch(void* const* d_in, const int* in_sizes, int n_in,
                              void* d_out, int out_size, void* d_ws, size_t ws_size,
                              hipStream_t stream)
{
    const float* em = (const float*)d_in[0];
    const float* trans = (const float*)d_in[1];
    int n_nodes = in_sizes[0] / 32;          // 262143
    int n_leaves = (n_nodes + 1) / 2;        // 131072
    int blocksA = n_leaves / 256;            // 512

    float* out512 = (float*)d_ws;            // 512*32 floats
    treecrf_bottom<<<dim3(blocksA), dim3(512), 0, stream>>>(em, trans, out512,
                                                            n_leaves);
    treecrf_top<<<dim3(1), dim3(1024), 0, stream>>>(out512, em, trans,
                                                    (float*)d_out);
}

// Round 7
// 98.948 us; speedup vs baseline: 1.1652x; 1.1652x over previous
//
#include <hip/hip_runtime.h>

// TreeCRF inside pass, L=32 channels, perfect binary tree (heap layout).
// parent[i] = em[i] + LSE_j(T[i,j]+left[j]) + LSE_j(T[i,j]+right[j])
// LSE_j(T[i,j]+c[j]) = m + log(sum_j E[i,j]*exp(c[j]-m)), E=exp(T), m=max_j c[j].
//
// R7: MFMA formulation. Per level, Y = E * C^T (32 x nc x 32) via
// mfma_f32_16x16x32_bf16: A = E rows (bf16, in registers, loaded once),
// B = exp-child rows straight out of LDS (bf16, 16B/lane contiguous).
// D layout (m89-verified): col = lane&15 = child q, row = (lane>>4)*4+reg = i.
// Epilogue per 16-child stripe: 8 logs, sibling pair-sum shfl_xor(1),
// em float4 add, 32-row max via shfl_xor(16/32), exp -> bf16 -> LDS row of
// the next level. LDS traffic per stripe: 1 ds_read_b128 + 2 ds_write_b64
// (vs ~512 broadcast b128 reads in R6's VALU formulation).

typedef float f32x4 __attribute__((ext_vector_type(4)));
typedef short s16x8 __attribute__((ext_vector_type(8)));
typedef short s16x4 __attribute__((ext_vector_type(4)));

__device__ __forceinline__ short f2bf(float f) {
    unsigned u = __builtin_bit_cast(unsigned, f);
    unsigned r = (u + 0x7fffu + ((u >> 16) & 1u)) >> 16;   // RNE to bf16
    return (short)r;
}

#define MSTEP(mask) { float4 o; o.x=__shfl_xor(r.x,mask); o.y=__shfl_xor(r.y,mask); \
                      o.z=__shfl_xor(r.z,mask); o.w=__shfl_xor(r.w,mask); \
                      r.x=fmaxf(r.x,o.x); r.y=fmaxf(r.y,o.y); \
                      r.z=fmaxf(r.z,o.z); r.w=fmaxf(r.w,o.w); }

template <int NT, int LEVELS>
__device__ __forceinline__ void run_tree(
    const int t, int Wp, int boff, const int b,
    const float* __restrict__ gchild,   // [2^LEVELS][32] leaf-level rows (f32)
    const float* __restrict__ em,
    const s16x8 a0, const s16x8 a1,     // E bf16 A-fragments (i 0..15 / 16..31)
    short* __restrict__ CA, float* __restrict__ MA,
    short* __restrict__ CB, float* __restrict__ MB,
    float* __restrict__ gout)           // [32]
{
    const int NC0 = 1 << LEVELS;
    // stage 0: global rows -> (max, exp row bf16) in CA/MA. 8 lanes per row.
    for (int u = t; u < NC0 * 8; u += NT) {
        int ql = u >> 3, k = u & 7;
        float4 x = ((const float4*)(gchild + (size_t)ql * 32))[k];
        float4 r = x;
        MSTEP(1) MSTEP(2) MSTEP(4)
        float m = fmaxf(fmaxf(r.x, r.y), fmaxf(r.z, r.w));
        s16x4 w;
        w[0] = f2bf(__expf(x.x - m)); w[1] = f2bf(__expf(x.y - m));
        w[2] = f2bf(__expf(x.z - m)); w[3] = f2bf(__expf(x.w - m));
        *((s16x4*)(CA + ql * 32 + k * 4)) = w;
        if (k == 0) MA[ql] = m;
    }
    __syncthreads();

    short* Cs = CA; float* Ms = MA;
    short* Cd = CB; float* Md = MB;
    const int lane = t & 63, wv = t >> 6, nw = NT / 64;
    const int ql = lane & 15, kg = lane >> 4;
    int nc = NC0;
    for (int l = 0; l < LEVELS; ++l) {
        int nqt = (nc >= 16) ? (nc >> 4) : 1;
        for (int qt = wv; qt < nqt; qt += nw) {
            int q = qt * 16 + ql;
            bool valid = q < nc;
            s16x8 bf = *((const s16x8*)(Cs + q * 32 + kg * 8));
            f32x4 d0 = {0.f, 0.f, 0.f, 0.f};
            f32x4 d1 = {0.f, 0.f, 0.f, 0.f};
            d0 = __builtin_amdgcn_mfma_f32_16x16x32_bf16(a0, bf, d0, 0, 0, 0);
            d1 = __builtin_amdgcn_mfma_f32_16x16x32_bf16(a1, bf, d1, 0, 0, 0);
            float mq = Ms[q];
            int p = qt * 8 + (ql >> 1);
            size_t node = (size_t)(Wp - 1) + (size_t)boff * b + p;
            const float4 e0 = *((const float4*)(em + node * 32 + kg * 4));
            const float4 e1 = *((const float4*)(em + node * 32 + 16 + kg * 4));
            float v0[4], v1[4];
#pragma unroll
        for (int r2 = 0; r2 < 4; ++r2) {
                float t0 = mq + __logf(d0[r2]);
                float t1 = mq + __logf(d1[r2]);
                v0[r2] = t0 + __shfl_xor(t0, 1);   // + sibling child (q^1)
                v1[r2] = t1 + __shfl_xor(t1, 1);
            }
            v0[0] += e0.x; v0[1] += e0.y; v0[2] += e0.z; v0[3] += e0.w;
            v1[0] += e1.x; v1[1] += e1.y; v1[2] += e1.z; v1[3] += e1.w;
            if (l == LEVELS - 1) {
                if (ql == 0) {                     // one parent: write 32 floats
                    float4 o0 = {v0[0], v0[1], v0[2], v0[3]};
                    float4 o1 = {v1[0], v1[1], v1[2], v1[3]};
                    *((float4*)(gout + kg * 4)) = o0;
                    *((float4*)(gout + 16 + kg * 4)) = o1;
                }
            } else {
                float m2 = fmaxf(fmaxf(fmaxf(v0[0], v0[1]), fmaxf(v0[2], v0[3])),
                                 fmaxf(fmaxf(v1[0], v1[1]), fmaxf(v1[2], v1[3])));
                m2 = fmaxf(m2, __shfl_xor(m2, 16));
                m2 = fmaxf(m2, __shfl_xor(m2, 32));  // max over all 32 rows i
                if (valid && !(ql & 1)) {
                    s16x4 w0, w1;
                    w0[0] = f2bf(__expf(v0[0] - m2)); w0[1] = f2bf(__expf(v0[1] - m2));
                    w0[2] = f2bf(__expf(v0[2] - m2)); w0[3] = f2bf(__expf(v0[3] - m2));
                    w1[0] = f2bf(__expf(v1[0] - m2)); w1[1] = f2bf(__expf(v1[1] - m2));
                    w1[2] = f2bf(__expf(v1[2] - m2)); w1[3] = f2bf(__expf(v1[3] - m2));
                    *((s16x4*)(Cd + p * 32 + kg * 4)) = w0;
                    *((s16x4*)(Cd + p * 32 + 16 + kg * 4)) = w1;
                    if (kg == 0) Md[p] = m2;
                }
            }
        }
        __syncthreads();
        short* tc = Cs; Cs = Cd; Cd = tc;
        float* tm = Ms; Ms = Md; Md = tm;
        nc >>= 1; Wp >>= 1; boff >>= 1;
    }
}

__device__ __forceinline__ void load_afrag(const float* __restrict__ trans,
                                           int row, int kg, s16x8* a)
{
#pragma unroll
    for (int j = 0; j < 8; ++j)
        (*a)[j] = f2bf(__expf(trans[row * 32 + kg * 8 + j]));
}

// Bottom: 512 blocks x 512 thr; 256 contiguous leaves -> one width-512 row.
__global__ __launch_bounds__(512) void treecrf_bottom(
    const float* __restrict__ em, const float* __restrict__ trans,
    float* __restrict__ out512, int n_leaves)
{
    __shared__ short CA[256 * 32];     // 16 KB
    __shared__ short CB[128 * 32];     // 8 KB
    __shared__ float MA[256];
    __shared__ float MB[128];
    int t = threadIdx.x, b = blockIdx.x;
    int ql = t & 15, kg = (t & 63) >> 4;
    s16x8 a0, a1;
    load_afrag(trans, ql, kg, &a0);
    load_afrag(trans, ql + 16, kg, &a1);
    run_tree<512, 8>(t, n_leaves >> 1, 128, b,
                     em + (size_t)(n_leaves - 1 + 256 * b) * 32, em, a0, a1,
                     CA, MA, CB, MB, out512 + (size_t)b * 32);
}

// Top: 1 block x 1024 thr; 512 width-512 rows -> root.
__global__ __launch_bounds__(1024) void treecrf_top(
    const float* __restrict__ g512, const float* __restrict__ em,
    const float* __restrict__ trans, float* __restrict__ out_root)
{
    __shared__ short CA[512 * 32];     // 32 KB
    __shared__ short CB[256 * 32];     // 16 KB
    __shared__ float MA[512];
    __shared__ float MB[256];
    int t = threadIdx.x;
    int ql = t & 15, kg = (t & 63) >> 4;
    s16x8 a0, a1;
    load_afrag(trans, ql, kg, &a0);
    load_afrag(trans, ql + 16, kg, &a1);
    run_tree<1024, 9>(t, 256, 0, 0, g512, em, a0, a1,
                      CA, MA, CB, MB, out_root);
}

extern "C" void kernel_launch(void* const* d_in, const int* in_sizes, int n_in,
                              void* d_out, int out_size, void* d_ws, size_t ws_size,
                              hipStream_t stream)
{
    const float* em = (const float*)d_in[0];
    const float* trans = (const float*)d_in[1];
    int n_nodes = in_sizes[0] / 32;          // 262143
    int n_leaves = (n_nodes + 1) / 2;        // 131072
    int blocksA = n_leaves / 256;            // 512

    float* out512 = (float*)d_ws;            // 512*32 floats
    treecrf_bottom<<<dim3(blocksA), dim3(512), 0, stream>>>(em, trans, out512,
                                                            n_leaves);
    treecrf_top<<<dim3(1), dim3(1024), 0, stream>>>(out512, em, trans,
                                                    (float*)d_out);
}